// Round 11
// baseline (338.364 us; speedup 1.0000x reference)
//
#include <hip/hip_runtime.h>
#include <hip/hip_bf16.h>
#include <hip/hip_fp16.h>
#include <math.h>

#define RESX 64
#define NVOX (RESX * RESX * RESX)   // 262144
#define FDIM 32
#define NMOD 3
#define HID 64
#define NCLS 4
#define NFREQ 6
#define INDIM 135                   // 96 + 3 + 36
#define TPB 64                      // points per block
#define XK 168                      // padded K-stride of X rows (f16); 336 B
#define XSTR 65                     // fallback LDS stride
#define MSTRIDE_B (NVOX * FDIM * 2) // module stride in BYTES (16 MiB)
#define NCELL 4096                  // 16^3 cells of 4^3 voxels
#define NREP 16                     // histogram replicas
#define NBT (NVOX / 128)            // 2048 transpose blocks per module
#define TRB (NMOD * NBT)            // 6144 transpose blocks
#define HISTB 2048                  // histogram blocks (x256 = 524288 pts)
#define PACKB 15                    // weight-pack blocks

typedef _Float16 f16x8 __attribute__((ext_vector_type(8)));
typedef float    f32x4 __attribute__((ext_vector_type(4)));

static __device__ __forceinline__ __half2 u2h(unsigned int u) {
    return __builtin_bit_cast(__half2, u);
}
static __device__ __forceinline__ unsigned int h2u(__half2 h) {
    return __builtin_bit_cast(unsigned int, h);
}

static __device__ __forceinline__ int cell_of(float px, float py, float pz) {
    int x0 = (int)floorf((px + 1.0f) * 0.5f * (RESX - 1));
    int y0 = (int)floorf((py + 1.0f) * 0.5f * (RESX - 1));
    int z0 = (int)floorf((pz + 1.0f) * 0.5f * (RESX - 1));
    x0 = min(max(x0, 0), RESX - 1);
    y0 = min(max(y0, 0), RESX - 1);
    z0 = min(max(z0, 0), RESX - 1);
    return ((z0 >> 2) << 8) | ((y0 >> 2) << 4) | (x0 >> 2);
}

#define W0PACK (5 * 4 * 64 * 8)     // 10240
#define W1PACK (2 * 4 * 64 * 8)     // 4096
#define W2PACK (2 * 64 * 8)         // 1024

// ---------------------------------------------------------------------------
// Merged pre-kernel: vectorized transpose -> f16 linear [m][voxel][32ch];
// replicated histogram; weight pack.   (unchanged from R9/R10)
// ---------------------------------------------------------------------------
__global__ void pre_kernel(const float* __restrict__ g,
                           _Float16* __restrict__ gt,
                           const float* __restrict__ W0,
                           const float* __restrict__ W1,
                           const float* __restrict__ W2,
                           _Float16* __restrict__ wb,
                           const float* __restrict__ points,
                           unsigned int* __restrict__ hist, int M) {
    __shared__ float4 tile4[FDIM][33];   // 16896 B; [channel][voxel/4]
    const int bid = blockIdx.x;
    const int t   = threadIdx.x;
    if (bid < TRB) {
        const int m  = bid / NBT;
        const int v0 = (bid % NBT) * 128;
        const float4* g4 = reinterpret_cast<const float4*>(g);
#pragma unroll
        for (int k = 0; k < 4; ++k) {
            const int idx = k * 256 + t;          // 0..1023 = 32ch x 32 float4
            const int c = idx >> 5, q = idx & 31;
            tile4[c][q] = g4[((size_t)(m * FDIM + c) * NVOX + v0) / 4 + q];
        }
        __syncthreads();
        uint4* gtu4 = reinterpret_cast<uint4*>(gt);
#pragma unroll
        for (int k = 0; k < 2; ++k) {
            const int idx = k * 256 + t;          // 0..511 = 128 vox x 4 uint4
            const int v = idx >> 2, q = idx & 3;  // channels 8q..8q+7
            const int vq = v >> 2, vr = v & 3;
            uint4 o;
            {
                const float a0 = reinterpret_cast<const float*>(&tile4[8 * q + 0][vq])[vr];
                const float a1 = reinterpret_cast<const float*>(&tile4[8 * q + 1][vq])[vr];
                const float a2 = reinterpret_cast<const float*>(&tile4[8 * q + 2][vq])[vr];
                const float a3 = reinterpret_cast<const float*>(&tile4[8 * q + 3][vq])[vr];
                const float a4 = reinterpret_cast<const float*>(&tile4[8 * q + 4][vq])[vr];
                const float a5 = reinterpret_cast<const float*>(&tile4[8 * q + 5][vq])[vr];
                const float a6 = reinterpret_cast<const float*>(&tile4[8 * q + 6][vq])[vr];
                const float a7 = reinterpret_cast<const float*>(&tile4[8 * q + 7][vq])[vr];
                o.x = h2u(__floats2half2_rn(a0, a1));
                o.y = h2u(__floats2half2_rn(a2, a3));
                o.z = h2u(__floats2half2_rn(a4, a5));
                o.w = h2u(__floats2half2_rn(a6, a7));
            }
            gtu4[(size_t)(m * NVOX + v0 + v) * 4 + q] = o;
        }
    } else if (bid < TRB + HISTB) {
        const int hb = bid - TRB;
        const int i  = hb * 256 + t;
        const int r  = hb & (NREP - 1);
        if (i < M) {
            const int c = cell_of(points[i * 3], points[i * 3 + 1], points[i * 3 + 2]);
            atomicAdd(&hist[r * NCELL + c], 1u);
        }
    } else {
        const int tt = (bid - TRB - HISTB) * 256 + t;
        const int NT = PACKB * 256;
        for (int idx = tt; idx < W0PACK; idx += NT) {
            const int j = idx & 7, l = (idx >> 3) & 63, nt = (idx >> 9) & 3, s = idx >> 11;
            const int k = 32 * s + (l >> 4) * 8 + j;
            const int o = 16 * nt + (l & 15);
            wb[idx] = (_Float16)((k < INDIM) ? W0[k * HID + o] : 0.0f);
        }
        for (int idx = tt; idx < W1PACK; idx += NT) {
            const int j = idx & 7, l = (idx >> 3) & 63, nt = (idx >> 9) & 3, s = idx >> 11;
            const int k = 32 * s + (l >> 4) * 8 + j;
            const int o = 16 * nt + (l & 15);
            wb[W0PACK + idx] = (_Float16)W1[k * HID + o];
        }
        for (int idx = tt; idx < W2PACK; idx += NT) {
            const int j = idx & 7, l = (idx >> 3) & 63, s = idx >> 9;
            const int k = 32 * s + (l >> 4) * 8 + j;
            const int o = l & 15;
            wb[W0PACK + W1PACK + idx] =
                (_Float16)((o < NCLS + 1) ? W2[k * (NCLS + 1) + o] : 0.0f);
        }
    }
}

// ---------------------------------------------------------------------------
// Scan (16 blocks): per-cell replica prefix + ATOMIC global cursor for cell
// bases (cell order is allocation-order; per-point outputs are position-
// independent so d_out stays deterministic).  hist becomes the live cursor.
// ---------------------------------------------------------------------------
__global__ void scan_rep_kernel(unsigned int* __restrict__ hist,
                                unsigned int* __restrict__ cursor) {
    const int c = blockIdx.x * 256 + threadIdx.x;   // 16 x 256 = 4096
    unsigned int run = 0;
#pragma unroll
    for (int r = 0; r < NREP; ++r) {
        const unsigned int v = hist[r * NCELL + c];
        hist[r * NCELL + c] = run;
        run += v;
    }
    const unsigned int base = atomicAdd(cursor, run);
#pragma unroll
    for (int r = 0; r < NREP; ++r) hist[r * NCELL + c] += base;
}

// ---------------------------------------------------------------------------
// Scatter: pos = atomicAdd(hist cursor); writes coalesced-readable pts4.
// ---------------------------------------------------------------------------
__global__ void scatter_kernel(const float* __restrict__ points,
                               unsigned int* __restrict__ hist,
                               float4* __restrict__ pts4, int M) {
    const int i = blockIdx.x * 256 + threadIdx.x;
    if (i < M) {
        const float px = points[i * 3], py = points[i * 3 + 1], pz = points[i * 3 + 2];
        const int c = cell_of(px, py, pz);
        const int r = blockIdx.x & (NREP - 1);      // matches pre_kernel mapping
        const unsigned int pos = atomicAdd(&hist[r * NCELL + c], 1u);
        pts4[pos] = make_float4(px, py, pz, __int_as_float(i));
    }
}

// ---------------------------------------------------------------------------
// Fused sample + PE + MFMA MLP (f16).  Barrier-free.  Gather phase is
// software-pipelined: ALL 96 loads issued before ANY interpolation math.
// ---------------------------------------------------------------------------
template <bool SORT>
__global__ __launch_bounds__(256, 7) void fused_mfma_kernel(
    const float* __restrict__ points,
    const float4* __restrict__ pts4,
    const _Float16* __restrict__ gt,
    const _Float16* __restrict__ wb,
    const float* __restrict__ b0, const float* __restrict__ b1,
    const float* __restrict__ b2,
    float* __restrict__ density, float* __restrict__ seg) {
    __shared__ __align__(16) _Float16 Xs[TPB * XK];   // 21504 B
    __shared__ __align__(16) uint4 PQ[TPB];           // {b00, fx|dy|dz, wab, wcd} 1024 B
    const int tid = threadIdx.x;
    const int chunk = gridDim.x >> 3;
    const int sbid  = (blockIdx.x & 7) * chunk + (blockIdx.x >> 3);
    const int p0    = sbid * TPB;

    const int l = tid & 63;
    const int w = __builtin_amdgcn_readfirstlane(tid >> 6);

    // ---------------- phase 1: per-point setup (lanes 0-15, once) ----------
    float px = 0.0f, py = 0.0f, pz = 0.0f;
    int gp = 0;
    if (l < 16) {
        const int p  = w * 16 + l;
        const int sp = p0 + p;
        if (SORT) {
            const float4 q = pts4[sp];
            px = q.x; py = q.y; pz = q.z; gp = __float_as_int(q.w);
        } else {
            px = points[sp * 3]; py = points[sp * 3 + 1]; pz = points[sp * 3 + 2];
            gp = sp;
        }
        const float ix = (px + 1.0f) * 0.5f * (RESX - 1);
        const float iy = (py + 1.0f) * 0.5f * (RESX - 1);
        const float iz = (pz + 1.0f) * 0.5f * (RESX - 1);
        const float fx0 = floorf(ix), fy0 = floorf(iy), fz0 = floorf(iz);
        const float fx = ix - fx0, fy = iy - fy0, fz = iz - fz0;
        int x0 = (int)fx0, y0 = (int)fy0, z0 = (int)fz0;
        x0 = min(max(x0, 0), RESX - 1);
        y0 = min(max(y0, 0), RESX - 1);
        z0 = min(max(z0, 0), RESX - 1);
        const float wy0 = 1.0f - fy, wy1 = fy;
        const float wz0 = 1.0f - fz, wz1 = fz;
        const unsigned int b00 = (unsigned int)((z0 * 4096 + y0 * 64 + x0) * 64);
        unsigned int code =
            (unsigned int)__builtin_bit_cast(unsigned short, __float2half(fx));
        if (y0 < RESX - 1) code |= 0x10000u;   // dy valid
        if (z0 < RESX - 1) code |= 0x20000u;   // dz valid
        PQ[w * 16 + l] = make_uint4(b00, code,
                                    h2u(__floats2half2_rn(wz0 * wy0, wz0 * wy1)),
                                    h2u(__floats2half2_rn(wz1 * wy0, wz1 * wy1)));
    }
    // (wave-local LDS RAW: hardware lgkmcnt ordering, no barrier needed)

    // ---------------- phase 2: pipelined packed-f16 gathers -----------------
    {
        const int hw   = tid >> 5;    // half-wave; wave w owns {2w, 2w+1}
        const int lane = tid & 31;
        const int half = lane >> 4;   // 0 => x0 voxel, 1 => x1 voxel (via lane*4)
        const char* gbase = reinterpret_cast<const char*>(gt) + lane * 4;
        const __half2 one2 = __float2half2_rn(1.0f);

        // stage A: all descriptors to registers (8 x b128 LDS reads)
        uint4 q[8];
#pragma unroll
        for (int i = 0; i < 8; ++i) q[i] = PQ[hw * 8 + i];

        // stage B: issue ALL 96 loads (fully static indices -> registers)
        unsigned int u[8][12];
#pragma unroll
        for (int i = 0; i < 8; ++i) {
            const unsigned int dy  = (q[i].y & 0x10000u) >> 4;   // 4096 B
            const unsigned int dz  = (q[i].y & 0x20000u) << 1;   // 262144 B
            const unsigned int b00 = q[i].x;
            const unsigned int b01 = b00 + dy;
            const unsigned int b10 = b00 + dz;
            const unsigned int b11 = b00 + dy + dz;
#pragma unroll
            for (int m = 0; m < NMOD; ++m) {
                const char* gm = gbase + (size_t)m * MSTRIDE_B;
                u[i][m * 4 + 0] = *reinterpret_cast<const unsigned int*>(gm + b00);
                u[i][m * 4 + 1] = *reinterpret_cast<const unsigned int*>(gm + b01);
                u[i][m * 4 + 2] = *reinterpret_cast<const unsigned int*>(gm + b10);
                u[i][m * 4 + 3] = *reinterpret_cast<const unsigned int*>(gm + b11);
            }
        }

        // stage C: interpolate + cross-half reduce + store
#pragma unroll
        for (int i = 0; i < 8; ++i) {
            const int p = hw * 8 + i;                 // in [16w, 16w+16)
            const __half fxh =
                __builtin_bit_cast(__half, (unsigned short)(q[i].y & 0xffffu));
            const __half2 fx2  = __half2half2(fxh);
            const __half2 wxh2 = half ? fx2 : __hsub2(one2, fx2);
            const __half2 wab = u2h(q[i].z);          // {w00, w01}
            const __half2 wcd = u2h(q[i].w);          // {w10, w11}
            const __half2 h00 = __hmul2(__low2half2(wab),  wxh2);
            const __half2 h01 = __hmul2(__high2half2(wab), wxh2);
            const __half2 h10 = __hmul2(__low2half2(wcd),  wxh2);
            const __half2 h11 = __hmul2(__high2half2(wcd), wxh2);
            unsigned int accu[NMOD];
#pragma unroll
            for (int m = 0; m < NMOD; ++m) {
                __half2 a = __hmul2(h00, u2h(u[i][m * 4 + 0]));
                a = __hfma2(h01, u2h(u[i][m * 4 + 1]), a);
                a = __hfma2(h10, u2h(u[i][m * 4 + 2]), a);
                a = __hfma2(h11, u2h(u[i][m * 4 + 3]), a);
                accu[m] = h2u(a);
            }
#pragma unroll
            for (int m = 0; m < NMOD; ++m) {
                const unsigned int other = __shfl_xor(accu[m], 16, 64);
                const __half2 sum = __hadd2(u2h(accu[m]), u2h(other));
                if (lane < 16) {
                    *reinterpret_cast<unsigned int*>(
                        &Xs[p * XK + m * FDIM + 2 * (lane & 15)]) = h2u(sum);
                }
            }
        }
    }

    // ---------------- phase 3: positional encoding (coords via shfl) -------
    {
        const int src = l & 15;                      // owner lane of this point
        const float c0 = __shfl(px, src, 64);
        const float c1 = __shfl(py, src, 64);
        const float c2 = __shfl(pz, src, 64);
        const int pt  = w * 16 + src;
        const int gq2 = l >> 4;
        const float c3[3] = {c0, c1, c2};
        _Float16* xr = &Xs[pt * XK];
        if (gq2 == 3) {
            xr[96]  = (_Float16)c3[0];
            xr[97]  = (_Float16)c3[1];
            xr[98]  = (_Float16)c3[2];
            xr[135] = (_Float16)0.0f;
        }
        if (gq2 == 2) {
            unsigned int* xz = reinterpret_cast<unsigned int*>(&xr[136]);  // cols 136..159
#pragma unroll
            for (int k = 0; k < 12; ++k) xz[k] = 0u;
        }
        {   // f = gq2
            const int f = gq2;
            const float hf = 0.5f * (float)(1 << f);
#pragma unroll
            for (int d = 0; d < 3; ++d) {
                const float r  = c3[d] * hf;
                const float rf = r - floorf(r);
                xr[99 + 6 * f + d]     = (_Float16)__builtin_amdgcn_sinf(rf);
                xr[99 + 6 * f + 3 + d] = (_Float16)__builtin_amdgcn_cosf(rf);
            }
        }
        if (gq2 < 2) {   // f = gq2 + 4
            const int f = gq2 + 4;
            const float hf = 0.5f * (float)(1 << f);
#pragma unroll
            for (int d = 0; d < 3; ++d) {
                const float r  = c3[d] * hf;
                const float rf = r - floorf(r);
                xr[99 + 6 * f + d]     = (_Float16)__builtin_amdgcn_sinf(rf);
                xr[99 + 6 * f + 3 + d] = (_Float16)__builtin_amdgcn_cosf(rf);
            }
        }
    }
    // No barrier: wave w's Xs rows written only by wave w.

    // ---------------- MFMA MLP (f16, wave-local) ----------------------------
    const int col = l & 15;
    const int g   = l >> 4;

    // ---- layer 0: 160 x 64, out h1 -> cols 96..159 ----
    f32x4 acc0[4];
#pragma unroll
    for (int nt = 0; nt < 4; ++nt) {
        const float bv = b0[nt * 16 + col];
        acc0[nt] = (f32x4){bv, bv, bv, bv};
    }
    {
        const _Float16* arow = &Xs[(w * 16 + col) * XK];
#pragma unroll
        for (int s = 0; s < 5; ++s) {
            const f16x8 af = *reinterpret_cast<const f16x8*>(arow + s * 32 + g * 8);
#pragma unroll
            for (int nt = 0; nt < 4; ++nt) {
                const f16x8 bfr = *reinterpret_cast<const f16x8*>(wb + (size_t)((s * 4 + nt) * 64 + l) * 8);
                acc0[nt] = __builtin_amdgcn_mfma_f32_16x16x32_f16(af, bfr, acc0[nt], 0, 0, 0);
            }
        }
    }
#pragma unroll
    for (int nt = 0; nt < 4; ++nt)
#pragma unroll
        for (int r = 0; r < 4; ++r) {
            Xs[(w * 16 + g * 4 + r) * XK + 96 + nt * 16 + col] =
                (_Float16)fmaxf(acc0[nt][r], 0.0f);
        }

    // ---- layer 1: 64 x 64, A = h1, out h2 -> cols 0..63 ----
    f32x4 acc1[4];
#pragma unroll
    for (int nt = 0; nt < 4; ++nt) {
        const float bv = b1[nt * 16 + col];
        acc1[nt] = (f32x4){bv, bv, bv, bv};
    }
    {
        const _Float16* arow = &Xs[(w * 16 + col) * XK + 96];
        const _Float16* wb1  = wb + W0PACK;
#pragma unroll
        for (int s = 0; s < 2; ++s) {
            const f16x8 af = *reinterpret_cast<const f16x8*>(arow + s * 32 + g * 8);
#pragma unroll
            for (int nt = 0; nt < 4; ++nt) {
                const f16x8 bfr = *reinterpret_cast<const f16x8*>(wb1 + (size_t)((s * 4 + nt) * 64 + l) * 8);
                acc1[nt] = __builtin_amdgcn_mfma_f32_16x16x32_f16(af, bfr, acc1[nt], 0, 0, 0);
            }
        }
    }
#pragma unroll
    for (int nt = 0; nt < 4; ++nt)
#pragma unroll
        for (int r = 0; r < 4; ++r) {
            Xs[(w * 16 + g * 4 + r) * XK + nt * 16 + col] =
                (_Float16)fmaxf(acc1[nt][r], 0.0f);
        }

    // ---- layer 2: 64 -> 5 (padded 16), A = h2 ----
    f32x4 acc2;
    {
        const float bv = (col < NCLS + 1) ? b2[col] : 0.0f;
        acc2 = (f32x4){bv, bv, bv, bv};
        const _Float16* arow = &Xs[(w * 16 + col) * XK];
        const _Float16* wb2  = wb + W0PACK + W1PACK;
#pragma unroll
        for (int s = 0; s < 2; ++s) {
            const f16x8 af  = *reinterpret_cast<const f16x8*>(arow + s * 32 + g * 8);
            const f16x8 bfr = *reinterpret_cast<const f16x8*>(wb2 + (size_t)(s * 64 + l) * 8);
            acc2 = __builtin_amdgcn_mfma_f32_16x16x32_f16(af, bfr, acc2, 0, 0, 0);
        }
    }
    if (col < NCLS + 1) {
        float* osr = reinterpret_cast<float*>(&Xs[0]);
#pragma unroll
        for (int r = 0; r < 4; ++r) {
            const int row = w * 16 + g * 4 + r;
            osr[(row * XK + 128) / 2 + col] = acc2[r];   // dead-h1 overlay, 16B-aligned
        }
    }

    // ---- epilogue: softplus + stores, 16 lanes per wave (own point) ----
    if (l < 16) {
        const int row = w * 16 + l;
        const float* osr = reinterpret_cast<const float*>(&Xs[0]) + (row * XK + 128) / 2;
        const float4 o0123 = *reinterpret_cast<const float4*>(osr);
        const float o4 = osr[4];
        const float e  = __builtin_amdgcn_exp2f(fabsf(o0123.x) * -1.44269504f);
        const float sp = fmaxf(o0123.x, 0.0f) + 0.69314718f * __builtin_amdgcn_logf(1.0f + e);
        density[gp] = sp;
        reinterpret_cast<float4*>(seg)[gp] = make_float4(o0123.y, o0123.z, o0123.w, o4);
    }
}

// ---------------------------------------------------------------------------
// Fallback (no workspace): f32 VALU path, original grid layout
// ---------------------------------------------------------------------------
__global__ __launch_bounds__(256, 4) void fused_nerf_fallback(
    const float* __restrict__ points,
    const float* __restrict__ grids,
    const float* __restrict__ W0, const float* __restrict__ b0,
    const float* __restrict__ W1, const float* __restrict__ b1,
    const float* __restrict__ W2, const float* __restrict__ b2,
    float* __restrict__ density, float* __restrict__ seg) {
    __shared__ float xT[INDIM + 1][XSTR];
    const int tid = threadIdx.x;
    const int p0  = blockIdx.x * TPB;
    {
        const int hw   = tid >> 5;
        const int lane = tid & 31;
        for (int i = 0; i < TPB / 8; ++i) {
            const int p  = hw * (TPB / 8) + i;
            const int gp = p0 + p;
            const float px = points[gp * 3 + 0];
            const float py = points[gp * 3 + 1];
            const float pz = points[gp * 3 + 2];
            const float ix = (px + 1.0f) * 0.5f * (RESX - 1);
            const float iy = (py + 1.0f) * 0.5f * (RESX - 1);
            const float iz = (pz + 1.0f) * 0.5f * (RESX - 1);
            const float fx0 = floorf(ix), fy0 = floorf(iy), fz0 = floorf(iz);
            const float fx = ix - fx0, fy = iy - fy0, fz = iz - fz0;
            int ix0 = (int)fx0, iy0 = (int)fy0, iz0 = (int)fz0;
            ix0 = min(max(ix0, 0), RESX - 1);
            iy0 = min(max(iy0, 0), RESX - 1);
            iz0 = min(max(iz0, 0), RESX - 1);
            const int ix1 = min(ix0 + 1, RESX - 1);
            const int iy1 = min(iy0 + 1, RESX - 1);
            const int iz1 = min(iz0 + 1, RESX - 1);
            const float wx1 = fx, wx0 = 1.0f - fx;
            const float wy1 = fy, wy0 = 1.0f - fy;
            const float wz1 = fz, wz0 = 1.0f - fz;
            const int vz0 = iz0 * 4096, vz1 = iz1 * 4096;
            const int vy0 = iy0 * 64,   vy1 = iy1 * 64;
            const int v000 = vz0 + vy0 + ix0, v001 = vz0 + vy0 + ix1;
            const int v010 = vz0 + vy1 + ix0, v011 = vz0 + vy1 + ix1;
            const int v100 = vz1 + vy0 + ix0, v101 = vz1 + vy0 + ix1;
            const int v110 = vz1 + vy1 + ix0, v111 = vz1 + vy1 + ix1;
            const float w000 = wz0 * wy0 * wx0, w001 = wz0 * wy0 * wx1;
            const float w010 = wz0 * wy1 * wx0, w011 = wz0 * wy1 * wx1;
            const float w100 = wz1 * wy0 * wx0, w101 = wz1 * wy0 * wx1;
            const float w110 = wz1 * wy1 * wx0, w111 = wz1 * wy1 * wx1;
#pragma unroll
            for (int m = 0; m < NMOD; ++m) {
                const float* gb = grids + (size_t)(m * FDIM + lane) * NVOX;
                float acc;
                acc = w000 * gb[v000];
                acc = fmaf(w001, gb[v001], acc);
                acc = fmaf(w010, gb[v010], acc);
                acc = fmaf(w011, gb[v011], acc);
                acc = fmaf(w100, gb[v100], acc);
                acc = fmaf(w101, gb[v101], acc);
                acc = fmaf(w110, gb[v110], acc);
                acc = fmaf(w111, gb[v111], acc);
                xT[m * FDIM + lane][p] = acc;
            }
        }
    }
    {
        const int p  = tid & 63;
        const int gq = tid >> 6;
        const int gp = p0 + p;
        float c3[3];
        c3[0] = points[gp * 3 + 0];
        c3[1] = points[gp * 3 + 1];
        c3[2] = points[gp * 3 + 2];
        if (gq == 3) {
#pragma unroll
            for (int d = 0; d < 3; ++d) xT[96 + d][p] = c3[d];
        }
#pragma unroll
        for (int f = 0; f < NFREQ; ++f) {
            if ((f & 3) != gq) continue;
            const float fr = (float)(1 << f);
#pragma unroll
            for (int d = 0; d < 3; ++d) {
                const float a = 3.14159274101257324f * fr * c3[d];
                xT[99 + 6 * f + d][p]     = sinf(a);
                xT[99 + 6 * f + 3 + d][p] = cosf(a);
            }
        }
    }
    __syncthreads();
    const int pl = tid & 63;
    const int wv = __builtin_amdgcn_readfirstlane(tid >> 6);
    const int gp = p0 + pl;
    float acc[16];
#pragma unroll
    for (int j = 0; j < 16; ++j) acc[j] = b0[wv * 16 + j];
    for (int k = 0; k < INDIM; ++k) {
        const float xk = xT[k][pl];
        const float* wr = W0 + k * HID + wv * 16;
#pragma unroll
        for (int j = 0; j < 16; ++j) acc[j] = fmaf(xk, wr[j], acc[j]);
    }
#pragma unroll
    for (int j = 0; j < 16; ++j) acc[j] = fmaxf(acc[j], 0.0f);
    __syncthreads();
#pragma unroll
    for (int j = 0; j < 16; ++j) xT[wv * 16 + j][pl] = acc[j];
    __syncthreads();
    float acc1[16];
#pragma unroll
    for (int j = 0; j < 16; ++j) acc1[j] = b1[wv * 16 + j];
    for (int k = 0; k < HID; ++k) {
        const float xk = xT[k][pl];
        const float* wr = W1 + k * HID + wv * 16;
#pragma unroll
        for (int j = 0; j < 16; ++j) acc1[j] = fmaf(xk, wr[j], acc1[j]);
    }
#pragma unroll
    for (int j = 0; j < 16; ++j) acc1[j] = fmaxf(acc1[j], 0.0f);
    __syncthreads();
#pragma unroll
    for (int j = 0; j < 16; ++j) xT[wv * 16 + j][pl] = acc1[j];
    __syncthreads();
    if (wv == 0) {
        float o[5];
#pragma unroll
        for (int j = 0; j < 5; ++j) o[j] = b2[j];
        for (int k = 0; k < HID; ++k) {
            const float xk = xT[k][pl];
            const float* wr = W2 + k * (1 + NCLS);
#pragma unroll
            for (int j = 0; j < 5; ++j) o[j] = fmaf(xk, wr[j], o[j]);
        }
        const float d = fmaxf(o[0], 0.0f) + log1pf(expf(-fabsf(o[0])));
        density[gp] = d;
        reinterpret_cast<float4*>(seg)[gp] = make_float4(o[1], o[2], o[3], o[4]);
    }
}

// ---------------------------------------------------------------------------
extern "C" void kernel_launch(void* const* d_in, const int* in_sizes, int n_in,
                              void* d_out, int out_size, void* d_ws, size_t ws_size,
                              hipStream_t stream) {
    const float* points = (const float*)d_in[0];
    const float* grids  = (const float*)d_in[1];
    const float* W0     = (const float*)d_in[2];
    const float* b0     = (const float*)d_in[3];
    const float* W1     = (const float*)d_in[4];
    const float* b1     = (const float*)d_in[5];
    const float* W2     = (const float*)d_in[6];
    const float* b2     = (const float*)d_in[7];

    const int M = in_sizes[0] / 3;               // 524288
    float* density = (float*)d_out;
    float* seg     = density + M;

    const size_t gt_b   = (size_t)NMOD * NVOX * FDIM * sizeof(_Float16);   // 48 MiB
    const size_t wb_b   = 32768;
    const size_t hist_b = (size_t)NREP * NCELL * sizeof(unsigned int);     // 256 KiB
    const size_t cur_b  = 16;                                              // atomic cursor
    const size_t pts_b  = (size_t)M * sizeof(float4);                      // 8 MiB
    const int nblk = M / TPB;

    if (ws_size >= gt_b + wb_b + hist_b + cur_b + pts_b) {
        char* p = (char*)d_ws;
        _Float16*     gt     = (_Float16*)p;      p += gt_b;
        _Float16*     wbp    = (_Float16*)p;      p += wb_b;
        unsigned int* hist   = (unsigned int*)p;  p += hist_b;
        unsigned int* cursor = (unsigned int*)p;  p += cur_b;
        float4*       pts4   = (float4*)p;

        hipMemsetAsync(hist, 0, hist_b + cur_b, stream);
        pre_kernel<<<TRB + HISTB + PACKB, 256, 0, stream>>>(
            grids, gt, W0, W1, W2, wbp, points, hist, M);
        scan_rep_kernel<<<NCELL / 256, 256, 0, stream>>>(hist, cursor);
        scatter_kernel<<<(M + 255) / 256, 256, 0, stream>>>(points, hist, pts4, M);
        fused_mfma_kernel<true><<<nblk, 256, 0, stream>>>(
            points, pts4, gt, wbp, b0, b1, b2, density, seg);
    } else if (ws_size >= gt_b + wb_b) {
        char* p = (char*)d_ws;
        _Float16* gt  = (_Float16*)p;  p += gt_b;
        _Float16* wbp = (_Float16*)p;
        pre_kernel<<<TRB + HISTB + PACKB, 256, 0, stream>>>(
            grids, gt, W0, W1, W2, wbp, points, (unsigned int*)nullptr, 0);
        fused_mfma_kernel<false><<<nblk, 256, 0, stream>>>(
            points, (const float4*)nullptr, gt, wbp, b0, b1, b2, density, seg);
    } else {
        fused_nerf_fallback<<<nblk, 256, 0, stream>>>(
            points, grids, W0, b0, W1, b1, W2, b2, density, seg);
    }
}

// Round 12
// 149.043 us; speedup vs baseline: 2.2702x; 2.2702x over previous
//
#include <hip/hip_runtime.h>
#include <hip/hip_bf16.h>
#include <hip/hip_fp16.h>
#include <math.h>

#define RESX 64
#define NVOX (RESX * RESX * RESX)   // 262144
#define FDIM 32
#define NMOD 3
#define HID 64
#define NCLS 4
#define NFREQ 6
#define INDIM 135                   // 96 + 3 + 36
#define TPB 64                      // points per block
#define XK 168                      // padded K-stride of X rows (f16); 336 B
#define XSTR 65                     // fallback LDS stride
#define MSTRIDE_B (NVOX * FDIM * 2) // module stride in BYTES (16 MiB)
#define NCELL 4096                  // 16^3 cells of 4^3 voxels
#define NREP 16                     // histogram replicas
#define NBT (NVOX / 128)            // 2048 transpose blocks per module
#define TRB (NMOD * NBT)            // 6144 transpose blocks
#define HISTB 2048                  // histogram blocks (x256 = 524288 pts)
#define PACKB 15                    // weight-pack blocks

typedef _Float16 f16x8 __attribute__((ext_vector_type(8)));
typedef float    f32x4 __attribute__((ext_vector_type(4)));

static __device__ __forceinline__ __half2 u2h(unsigned int u) {
    return __builtin_bit_cast(__half2, u);
}
static __device__ __forceinline__ unsigned int h2u(__half2 h) {
    return __builtin_bit_cast(unsigned int, h);
}

static __device__ __forceinline__ int cell_of(float px, float py, float pz) {
    int x0 = (int)floorf((px + 1.0f) * 0.5f * (RESX - 1));
    int y0 = (int)floorf((py + 1.0f) * 0.5f * (RESX - 1));
    int z0 = (int)floorf((pz + 1.0f) * 0.5f * (RESX - 1));
    x0 = min(max(x0, 0), RESX - 1);
    y0 = min(max(y0, 0), RESX - 1);
    z0 = min(max(z0, 0), RESX - 1);
    return ((z0 >> 2) << 8) | ((y0 >> 2) << 4) | (x0 >> 2);
}

#define W0PACK (5 * 4 * 64 * 8)     // 10240
#define W1PACK (2 * 4 * 64 * 8)     // 4096
#define W2PACK (2 * 64 * 8)         // 1024

// ---------------------------------------------------------------------------
// Merged pre-kernel: vectorized transpose -> f16 linear [m][voxel][32ch];
// replicated histogram; weight pack.
// ---------------------------------------------------------------------------
__global__ void pre_kernel(const float* __restrict__ g,
                           _Float16* __restrict__ gt,
                           const float* __restrict__ W0,
                           const float* __restrict__ W1,
                           const float* __restrict__ W2,
                           _Float16* __restrict__ wb,
                           const float* __restrict__ points,
                           unsigned int* __restrict__ hist, int M) {
    __shared__ float4 tile4[FDIM][33];   // 16896 B; [channel][voxel/4]
    const int bid = blockIdx.x;
    const int t   = threadIdx.x;
    if (bid < TRB) {
        const int m  = bid / NBT;
        const int v0 = (bid % NBT) * 128;
        const float4* g4 = reinterpret_cast<const float4*>(g);
#pragma unroll
        for (int k = 0; k < 4; ++k) {
            const int idx = k * 256 + t;          // 0..1023 = 32ch x 32 float4
            const int c = idx >> 5, q = idx & 31;
            tile4[c][q] = g4[((size_t)(m * FDIM + c) * NVOX + v0) / 4 + q];
        }
        __syncthreads();
        uint4* gtu4 = reinterpret_cast<uint4*>(gt);
#pragma unroll
        for (int k = 0; k < 2; ++k) {
            const int idx = k * 256 + t;          // 0..511 = 128 vox x 4 uint4
            const int v = idx >> 2, q = idx & 3;  // channels 8q..8q+7
            const int vq = v >> 2, vr = v & 3;
            uint4 o;
            {
                const float a0 = reinterpret_cast<const float*>(&tile4[8 * q + 0][vq])[vr];
                const float a1 = reinterpret_cast<const float*>(&tile4[8 * q + 1][vq])[vr];
                const float a2 = reinterpret_cast<const float*>(&tile4[8 * q + 2][vq])[vr];
                const float a3 = reinterpret_cast<const float*>(&tile4[8 * q + 3][vq])[vr];
                const float a4 = reinterpret_cast<const float*>(&tile4[8 * q + 4][vq])[vr];
                const float a5 = reinterpret_cast<const float*>(&tile4[8 * q + 5][vq])[vr];
                const float a6 = reinterpret_cast<const float*>(&tile4[8 * q + 6][vq])[vr];
                const float a7 = reinterpret_cast<const float*>(&tile4[8 * q + 7][vq])[vr];
                o.x = h2u(__floats2half2_rn(a0, a1));
                o.y = h2u(__floats2half2_rn(a2, a3));
                o.z = h2u(__floats2half2_rn(a4, a5));
                o.w = h2u(__floats2half2_rn(a6, a7));
            }
            gtu4[(size_t)(m * NVOX + v0 + v) * 4 + q] = o;
        }
    } else if (bid < TRB + HISTB) {
        const int hb = bid - TRB;
        const int i  = hb * 256 + t;
        const int r  = hb & (NREP - 1);
        if (i < M) {
            const int c = cell_of(points[i * 3], points[i * 3 + 1], points[i * 3 + 2]);
            atomicAdd(&hist[r * NCELL + c], 1u);
        }
    } else {
        const int tt = (bid - TRB - HISTB) * 256 + t;
        const int NT = PACKB * 256;
        for (int idx = tt; idx < W0PACK; idx += NT) {
            const int j = idx & 7, l = (idx >> 3) & 63, nt = (idx >> 9) & 3, s = idx >> 11;
            const int k = 32 * s + (l >> 4) * 8 + j;
            const int o = 16 * nt + (l & 15);
            wb[idx] = (_Float16)((k < INDIM) ? W0[k * HID + o] : 0.0f);
        }
        for (int idx = tt; idx < W1PACK; idx += NT) {
            const int j = idx & 7, l = (idx >> 3) & 63, nt = (idx >> 9) & 3, s = idx >> 11;
            const int k = 32 * s + (l >> 4) * 8 + j;
            const int o = 16 * nt + (l & 15);
            wb[W0PACK + idx] = (_Float16)W1[k * HID + o];
        }
        for (int idx = tt; idx < W2PACK; idx += NT) {
            const int j = idx & 7, l = (idx >> 3) & 63, s = idx >> 9;
            const int k = 32 * s + (l >> 4) * 8 + j;
            const int o = l & 15;
            wb[W0PACK + W1PACK + idx] =
                (_Float16)((o < NCLS + 1) ? W2[k * (NCLS + 1) + o] : 0.0f);
        }
    }
}

// ---------------------------------------------------------------------------
// Scan (16 blocks): per-cell replica prefix + atomic global cursor for cell
// bases.  hist becomes the live scatter cursor.  (R11 pre-chain, kept)
// ---------------------------------------------------------------------------
__global__ void scan_rep_kernel(unsigned int* __restrict__ hist,
                                unsigned int* __restrict__ cursor) {
    const int c = blockIdx.x * 256 + threadIdx.x;   // 16 x 256 = 4096
    unsigned int run = 0;
#pragma unroll
    for (int r = 0; r < NREP; ++r) {
        const unsigned int v = hist[r * NCELL + c];
        hist[r * NCELL + c] = run;
        run += v;
    }
    const unsigned int base = atomicAdd(cursor, run);
#pragma unroll
    for (int r = 0; r < NREP; ++r) hist[r * NCELL + c] += base;
}

// ---------------------------------------------------------------------------
// Scatter: pos = atomicAdd(hist cursor); writes coalesced-readable pts4.
// ---------------------------------------------------------------------------
__global__ void scatter_kernel(const float* __restrict__ points,
                               unsigned int* __restrict__ hist,
                               float4* __restrict__ pts4, int M) {
    const int i = blockIdx.x * 256 + threadIdx.x;
    if (i < M) {
        const float px = points[i * 3], py = points[i * 3 + 1], pz = points[i * 3 + 2];
        const int c = cell_of(px, py, pz);
        const int r = blockIdx.x & (NREP - 1);      // matches pre_kernel mapping
        const unsigned int pos = atomicAdd(&hist[r * NCELL + c], 1u);
        pts4[pos] = make_float4(px, py, pz, __int_as_float(i));
    }
}

// ---------------------------------------------------------------------------
// Fused sample + PE + MFMA MLP (f16).  Barrier-free.
// Phase 2: depth-2 ping-pong pipeline (prefetch i+1's 12 loads while
// consuming i) -- fits the 7-wave VGPR budget (~73), unlike R11's depth-8.
// ---------------------------------------------------------------------------
template <bool SORT>
__global__ __launch_bounds__(256, 7) void fused_mfma_kernel(
    const float* __restrict__ points,
    const float4* __restrict__ pts4,
    const _Float16* __restrict__ gt,
    const _Float16* __restrict__ wb,
    const float* __restrict__ b0, const float* __restrict__ b1,
    const float* __restrict__ b2,
    float* __restrict__ density, float* __restrict__ seg) {
    __shared__ __align__(16) _Float16 Xs[TPB * XK];   // 21504 B
    __shared__ __align__(16) uint4 PQ[TPB];           // {b00, fx|dy|dz, wab, wcd} 1024 B
    const int tid = threadIdx.x;
    const int chunk = gridDim.x >> 3;
    const int sbid  = (blockIdx.x & 7) * chunk + (blockIdx.x >> 3);
    const int p0    = sbid * TPB;

    const int l = tid & 63;
    const int w = __builtin_amdgcn_readfirstlane(tid >> 6);

    // ---------------- phase 1: per-point setup (lanes 0-15, once) ----------
    float px = 0.0f, py = 0.0f, pz = 0.0f;
    int gp = 0;
    if (l < 16) {
        const int p  = w * 16 + l;
        const int sp = p0 + p;
        if (SORT) {
            const float4 q = pts4[sp];
            px = q.x; py = q.y; pz = q.z; gp = __float_as_int(q.w);
        } else {
            px = points[sp * 3]; py = points[sp * 3 + 1]; pz = points[sp * 3 + 2];
            gp = sp;
        }
        const float ix = (px + 1.0f) * 0.5f * (RESX - 1);
        const float iy = (py + 1.0f) * 0.5f * (RESX - 1);
        const float iz = (pz + 1.0f) * 0.5f * (RESX - 1);
        const float fx0 = floorf(ix), fy0 = floorf(iy), fz0 = floorf(iz);
        const float fx = ix - fx0, fy = iy - fy0, fz = iz - fz0;
        int x0 = (int)fx0, y0 = (int)fy0, z0 = (int)fz0;
        x0 = min(max(x0, 0), RESX - 1);
        y0 = min(max(y0, 0), RESX - 1);
        z0 = min(max(z0, 0), RESX - 1);
        const float wy0 = 1.0f - fy, wy1 = fy;
        const float wz0 = 1.0f - fz, wz1 = fz;
        const unsigned int b00 = (unsigned int)((z0 * 4096 + y0 * 64 + x0) * 64);
        unsigned int code =
            (unsigned int)__builtin_bit_cast(unsigned short, __float2half(fx));
        if (y0 < RESX - 1) code |= 0x10000u;   // dy valid
        if (z0 < RESX - 1) code |= 0x20000u;   // dz valid
        PQ[w * 16 + l] = make_uint4(b00, code,
                                    h2u(__floats2half2_rn(wz0 * wy0, wz0 * wy1)),
                                    h2u(__floats2half2_rn(wz1 * wy0, wz1 * wy1)));
    }
    // (wave-local LDS RAW: hardware lgkmcnt ordering, no barrier needed)

    // ---------------- phase 2: depth-2 pipelined packed-f16 gathers ---------
    {
        const int hw   = tid >> 5;    // half-wave; wave w owns {2w, 2w+1}
        const int lane = tid & 31;
        const int half = lane >> 4;   // 0 => x0 voxel, 1 => x1 voxel (via lane*4)
        const char* gbase = reinterpret_cast<const char*>(gt) + lane * 4;
        const __half2 one2 = __float2half2_rn(1.0f);

        uint4 qA;
        unsigned int uA[12];
        // prologue: load descriptor + issue loads for i = 0
        qA = PQ[hw * 8 + 0];
        {
            const unsigned int dy  = (qA.y & 0x10000u) >> 4;   // 4096 B
            const unsigned int dz  = (qA.y & 0x20000u) << 1;   // 262144 B
            const unsigned int b00 = qA.x;
            const unsigned int b01 = b00 + dy;
            const unsigned int b10 = b00 + dz;
            const unsigned int b11 = b00 + dy + dz;
#pragma unroll
            for (int m = 0; m < NMOD; ++m) {
                const char* gm = gbase + (size_t)m * MSTRIDE_B;
                uA[m * 4 + 0] = *reinterpret_cast<const unsigned int*>(gm + b00);
                uA[m * 4 + 1] = *reinterpret_cast<const unsigned int*>(gm + b01);
                uA[m * 4 + 2] = *reinterpret_cast<const unsigned int*>(gm + b10);
                uA[m * 4 + 3] = *reinterpret_cast<const unsigned int*>(gm + b11);
            }
        }
#pragma unroll
        for (int i = 0; i < 8; ++i) {
            // prefetch i+1 (issued BEFORE consuming i; SSA-renamed, no copies)
            uint4 qB = qA;
            unsigned int uB[12];
            if (i < 7) {
                qB = PQ[hw * 8 + i + 1];
                const unsigned int dy  = (qB.y & 0x10000u) >> 4;
                const unsigned int dz  = (qB.y & 0x20000u) << 1;
                const unsigned int b00 = qB.x;
                const unsigned int b01 = b00 + dy;
                const unsigned int b10 = b00 + dz;
                const unsigned int b11 = b00 + dy + dz;
#pragma unroll
                for (int m = 0; m < NMOD; ++m) {
                    const char* gm = gbase + (size_t)m * MSTRIDE_B;
                    uB[m * 4 + 0] = *reinterpret_cast<const unsigned int*>(gm + b00);
                    uB[m * 4 + 1] = *reinterpret_cast<const unsigned int*>(gm + b01);
                    uB[m * 4 + 2] = *reinterpret_cast<const unsigned int*>(gm + b10);
                    uB[m * 4 + 3] = *reinterpret_cast<const unsigned int*>(gm + b11);
                }
            }
            // consume i
            {
                const int p = hw * 8 + i;             // in [16w, 16w+16)
                const __half fxh =
                    __builtin_bit_cast(__half, (unsigned short)(qA.y & 0xffffu));
                const __half2 fx2  = __half2half2(fxh);
                const __half2 wxh2 = half ? fx2 : __hsub2(one2, fx2);
                const __half2 wab = u2h(qA.z);        // {w00, w01}
                const __half2 wcd = u2h(qA.w);        // {w10, w11}
                const __half2 h00 = __hmul2(__low2half2(wab),  wxh2);
                const __half2 h01 = __hmul2(__high2half2(wab), wxh2);
                const __half2 h10 = __hmul2(__low2half2(wcd),  wxh2);
                const __half2 h11 = __hmul2(__high2half2(wcd), wxh2);
                unsigned int accu[NMOD];
#pragma unroll
                for (int m = 0; m < NMOD; ++m) {
                    __half2 a = __hmul2(h00, u2h(uA[m * 4 + 0]));
                    a = __hfma2(h01, u2h(uA[m * 4 + 1]), a);
                    a = __hfma2(h10, u2h(uA[m * 4 + 2]), a);
                    a = __hfma2(h11, u2h(uA[m * 4 + 3]), a);
                    accu[m] = h2u(a);
                }
#pragma unroll
                for (int m = 0; m < NMOD; ++m) {
                    const unsigned int other = __shfl_xor(accu[m], 16, 64);
                    const __half2 sum = __hadd2(u2h(accu[m]), u2h(other));
                    if (lane < 16) {
                        *reinterpret_cast<unsigned int*>(
                            &Xs[p * XK + m * FDIM + 2 * (lane & 15)]) = h2u(sum);
                    }
                }
            }
            // rotate (SSA rename under full unroll)
            if (i < 7) {
                qA = qB;
#pragma unroll
                for (int k = 0; k < 12; ++k) uA[k] = uB[k];
            }
        }
    }

    // ---------------- phase 3: positional encoding (coords via shfl) -------
    {
        const int src = l & 15;                      // owner lane of this point
        const float c0 = __shfl(px, src, 64);
        const float c1 = __shfl(py, src, 64);
        const float c2 = __shfl(pz, src, 64);
        const int pt  = w * 16 + src;
        const int gq2 = l >> 4;
        const float c3[3] = {c0, c1, c2};
        _Float16* xr = &Xs[pt * XK];
        if (gq2 == 3) {
            xr[96]  = (_Float16)c3[0];
            xr[97]  = (_Float16)c3[1];
            xr[98]  = (_Float16)c3[2];
            xr[135] = (_Float16)0.0f;
        }
        if (gq2 == 2) {
            unsigned int* xz = reinterpret_cast<unsigned int*>(&xr[136]);  // cols 136..159
#pragma unroll
            for (int k = 0; k < 12; ++k) xz[k] = 0u;
        }
        {   // f = gq2
            const int f = gq2;
            const float hf = 0.5f * (float)(1 << f);
#pragma unroll
            for (int d = 0; d < 3; ++d) {
                const float r  = c3[d] * hf;
                const float rf = r - floorf(r);
                xr[99 + 6 * f + d]     = (_Float16)__builtin_amdgcn_sinf(rf);
                xr[99 + 6 * f + 3 + d] = (_Float16)__builtin_amdgcn_cosf(rf);
            }
        }
        if (gq2 < 2) {   // f = gq2 + 4
            const int f = gq2 + 4;
            const float hf = 0.5f * (float)(1 << f);
#pragma unroll
            for (int d = 0; d < 3; ++d) {
                const float r  = c3[d] * hf;
                const float rf = r - floorf(r);
                xr[99 + 6 * f + d]     = (_Float16)__builtin_amdgcn_sinf(rf);
                xr[99 + 6 * f + 3 + d] = (_Float16)__builtin_amdgcn_cosf(rf);
            }
        }
    }
    // No barrier: wave w's Xs rows written only by wave w.

    // ---------------- MFMA MLP (f16, wave-local) ----------------------------
    const int col = l & 15;
    const int g   = l >> 4;

    // ---- layer 0: 160 x 64, out h1 -> cols 96..159 ----
    f32x4 acc0[4];
#pragma unroll
    for (int nt = 0; nt < 4; ++nt) {
        const float bv = b0[nt * 16 + col];
        acc0[nt] = (f32x4){bv, bv, bv, bv};
    }
    {
        const _Float16* arow = &Xs[(w * 16 + col) * XK];
#pragma unroll
        for (int s = 0; s < 5; ++s) {
            const f16x8 af = *reinterpret_cast<const f16x8*>(arow + s * 32 + g * 8);
#pragma unroll
            for (int nt = 0; nt < 4; ++nt) {
                const f16x8 bfr = *reinterpret_cast<const f16x8*>(wb + (size_t)((s * 4 + nt) * 64 + l) * 8);
                acc0[nt] = __builtin_amdgcn_mfma_f32_16x16x32_f16(af, bfr, acc0[nt], 0, 0, 0);
            }
        }
    }
#pragma unroll
    for (int nt = 0; nt < 4; ++nt)
#pragma unroll
        for (int r = 0; r < 4; ++r) {
            Xs[(w * 16 + g * 4 + r) * XK + 96 + nt * 16 + col] =
                (_Float16)fmaxf(acc0[nt][r], 0.0f);
        }

    // ---- layer 1: 64 x 64, A = h1, out h2 -> cols 0..63 ----
    f32x4 acc1[4];
#pragma unroll
    for (int nt = 0; nt < 4; ++nt) {
        const float bv = b1[nt * 16 + col];
        acc1[nt] = (f32x4){bv, bv, bv, bv};
    }
    {
        const _Float16* arow = &Xs[(w * 16 + col) * XK + 96];
        const _Float16* wb1  = wb + W0PACK;
#pragma unroll
        for (int s = 0; s < 2; ++s) {
            const f16x8 af = *reinterpret_cast<const f16x8*>(arow + s * 32 + g * 8);
#pragma unroll
            for (int nt = 0; nt < 4; ++nt) {
                const f16x8 bfr = *reinterpret_cast<const f16x8*>(wb1 + (size_t)((s * 4 + nt) * 64 + l) * 8);
                acc1[nt] = __builtin_amdgcn_mfma_f32_16x16x32_f16(af, bfr, acc1[nt], 0, 0, 0);
            }
        }
    }
#pragma unroll
    for (int nt = 0; nt < 4; ++nt)
#pragma unroll
        for (int r = 0; r < 4; ++r) {
            Xs[(w * 16 + g * 4 + r) * XK + nt * 16 + col] =
                (_Float16)fmaxf(acc1[nt][r], 0.0f);
        }

    // ---- layer 2: 64 -> 5 (padded 16), A = h2 ----
    f32x4 acc2;
    {
        const float bv = (col < NCLS + 1) ? b2[col] : 0.0f;
        acc2 = (f32x4){bv, bv, bv, bv};
        const _Float16* arow = &Xs[(w * 16 + col) * XK];
        const _Float16* wb2  = wb + W0PACK + W1PACK;
#pragma unroll
        for (int s = 0; s < 2; ++s) {
            const f16x8 af  = *reinterpret_cast<const f16x8*>(arow + s * 32 + g * 8);
            const f16x8 bfr = *reinterpret_cast<const f16x8*>(wb2 + (size_t)(s * 64 + l) * 8);
            acc2 = __builtin_amdgcn_mfma_f32_16x16x32_f16(af, bfr, acc2, 0, 0, 0);
        }
    }
    if (col < NCLS + 1) {
        float* osr = reinterpret_cast<float*>(&Xs[0]);
#pragma unroll
        for (int r = 0; r < 4; ++r) {
            const int row = w * 16 + g * 4 + r;
            osr[(row * XK + 128) / 2 + col] = acc2[r];   // dead-h1 overlay, 16B-aligned
        }
    }

    // ---- epilogue: softplus + stores, 16 lanes per wave (own point) ----
    if (l < 16) {
        const int row = w * 16 + l;
        const float* osr = reinterpret_cast<const float*>(&Xs[0]) + (row * XK + 128) / 2;
        const float4 o0123 = *reinterpret_cast<const float4*>(osr);
        const float o4 = osr[4];
        const float e  = __builtin_amdgcn_exp2f(fabsf(o0123.x) * -1.44269504f);
        const float sp = fmaxf(o0123.x, 0.0f) + 0.69314718f * __builtin_amdgcn_logf(1.0f + e);
        density[gp] = sp;
        reinterpret_cast<float4*>(seg)[gp] = make_float4(o0123.y, o0123.z, o0123.w, o4);
    }
}

// ---------------------------------------------------------------------------
// Fallback (no workspace): f32 VALU path, original grid layout
// ---------------------------------------------------------------------------
__global__ __launch_bounds__(256, 4) void fused_nerf_fallback(
    const float* __restrict__ points,
    const float* __restrict__ grids,
    const float* __restrict__ W0, const float* __restrict__ b0,
    const float* __restrict__ W1, const float* __restrict__ b1,
    const float* __restrict__ W2, const float* __restrict__ b2,
    float* __restrict__ density, float* __restrict__ seg) {
    __shared__ float xT[INDIM + 1][XSTR];
    const int tid = threadIdx.x;
    const int p0  = blockIdx.x * TPB;
    {
        const int hw   = tid >> 5;
        const int lane = tid & 31;
        for (int i = 0; i < TPB / 8; ++i) {
            const int p  = hw * (TPB / 8) + i;
            const int gp = p0 + p;
            const float px = points[gp * 3 + 0];
            const float py = points[gp * 3 + 1];
            const float pz = points[gp * 3 + 2];
            const float ix = (px + 1.0f) * 0.5f * (RESX - 1);
            const float iy = (py + 1.0f) * 0.5f * (RESX - 1);
            const float iz = (pz + 1.0f) * 0.5f * (RESX - 1);
            const float fx0 = floorf(ix), fy0 = floorf(iy), fz0 = floorf(iz);
            const float fx = ix - fx0, fy = iy - fy0, fz = iz - fz0;
            int ix0 = (int)fx0, iy0 = (int)fy0, iz0 = (int)fz0;
            ix0 = min(max(ix0, 0), RESX - 1);
            iy0 = min(max(iy0, 0), RESX - 1);
            iz0 = min(max(iz0, 0), RESX - 1);
            const int ix1 = min(ix0 + 1, RESX - 1);
            const int iy1 = min(iy0 + 1, RESX - 1);
            const int iz1 = min(iz0 + 1, RESX - 1);
            const float wx1 = fx, wx0 = 1.0f - fx;
            const float wy1 = fy, wy0 = 1.0f - fy;
            const float wz1 = fz, wz0 = 1.0f - fz;
            const int vz0 = iz0 * 4096, vz1 = iz1 * 4096;
            const int vy0 = iy0 * 64,   vy1 = iy1 * 64;
            const int v000 = vz0 + vy0 + ix0, v001 = vz0 + vy0 + ix1;
            const int v010 = vz0 + vy1 + ix0, v011 = vz0 + vy1 + ix1;
            const int v100 = vz1 + vy0 + ix0, v101 = vz1 + vy0 + ix1;
            const int v110 = vz1 + vy1 + ix0, v111 = vz1 + vy1 + ix1;
            const float w000 = wz0 * wy0 * wx0, w001 = wz0 * wy0 * wx1;
            const float w010 = wz0 * wy1 * wx0, w011 = wz0 * wy1 * wx1;
            const float w100 = wz1 * wy0 * wx0, w101 = wz1 * wy0 * wx1;
            const float w110 = wz1 * wy1 * wx0, w111 = wz1 * wy1 * wx1;
#pragma unroll
            for (int m = 0; m < NMOD; ++m) {
                const float* gb = grids + (size_t)(m * FDIM + lane) * NVOX;
                float acc;
                acc = w000 * gb[v000];
                acc = fmaf(w001, gb[v001], acc);
                acc = fmaf(w010, gb[v010], acc);
                acc = fmaf(w011, gb[v011], acc);
                acc = fmaf(w100, gb[v100], acc);
                acc = fmaf(w101, gb[v101], acc);
                acc = fmaf(w110, gb[v110], acc);
                acc = fmaf(w111, gb[v111], acc);
                xT[m * FDIM + lane][p] = acc;
            }
        }
    }
    {
        const int p  = tid & 63;
        const int gq = tid >> 6;
        const int gp = p0 + p;
        float c3[3];
        c3[0] = points[gp * 3 + 0];
        c3[1] = points[gp * 3 + 1];
        c3[2] = points[gp * 3 + 2];
        if (gq == 3) {
#pragma unroll
            for (int d = 0; d < 3; ++d) xT[96 + d][p] = c3[d];
        }
#pragma unroll
        for (int f = 0; f < NFREQ; ++f) {
            if ((f & 3) != gq) continue;
            const float fr = (float)(1 << f);
#pragma unroll
            for (int d = 0; d < 3; ++d) {
                const float a = 3.14159274101257324f * fr * c3[d];
                xT[99 + 6 * f + d][p]     = sinf(a);
                xT[99 + 6 * f + 3 + d][p] = cosf(a);
            }
        }
    }
    __syncthreads();
    const int pl = tid & 63;
    const int wv = __builtin_amdgcn_readfirstlane(tid >> 6);
    const int gp = p0 + pl;
    float acc[16];
#pragma unroll
    for (int j = 0; j < 16; ++j) acc[j] = b0[wv * 16 + j];
    for (int k = 0; k < INDIM; ++k) {
        const float xk = xT[k][pl];
        const float* wr = W0 + k * HID + wv * 16;
#pragma unroll
        for (int j = 0; j < 16; ++j) acc[j] = fmaf(xk, wr[j], acc[j]);
    }
#pragma unroll
    for (int j = 0; j < 16; ++j) acc[j] = fmaxf(acc[j], 0.0f);
    __syncthreads();
#pragma unroll
    for (int j = 0; j < 16; ++j) xT[wv * 16 + j][pl] = acc[j];
    __syncthreads();
    float acc1[16];
#pragma unroll
    for (int j = 0; j < 16; ++j) acc1[j] = b1[wv * 16 + j];
    for (int k = 0; k < HID; ++k) {
        const float xk = xT[k][pl];
        const float* wr = W1 + k * HID + wv * 16;
#pragma unroll
        for (int j = 0; j < 16; ++j) acc1[j] = fmaf(xk, wr[j], acc1[j]);
    }
#pragma unroll
    for (int j = 0; j < 16; ++j) acc1[j] = fmaxf(acc1[j], 0.0f);
    __syncthreads();
#pragma unroll
    for (int j = 0; j < 16; ++j) xT[wv * 16 + j][pl] = acc1[j];
    __syncthreads();
    if (wv == 0) {
        float o[5];
#pragma unroll
        for (int j = 0; j < 5; ++j) o[j] = b2[j];
        for (int k = 0; k < HID; ++k) {
            const float xk = xT[k][pl];
            const float* wr = W2 + k * (1 + NCLS);
#pragma unroll
            for (int j = 0; j < 5; ++j) o[j] = fmaf(xk, wr[j], o[j]);
        }
        const float d = fmaxf(o[0], 0.0f) + log1pf(expf(-fabsf(o[0])));
        density[gp] = d;
        reinterpret_cast<float4*>(seg)[gp] = make_float4(o[1], o[2], o[3], o[4]);
    }
}

// ---------------------------------------------------------------------------
extern "C" void kernel_launch(void* const* d_in, const int* in_sizes, int n_in,
                              void* d_out, int out_size, void* d_ws, size_t ws_size,
                              hipStream_t stream) {
    const float* points = (const float*)d_in[0];
    const float* grids  = (const float*)d_in[1];
    const float* W0     = (const float*)d_in[2];
    const float* b0     = (const float*)d_in[3];
    const float* W1     = (const float*)d_in[4];
    const float* b1     = (const float*)d_in[5];
    const float* W2     = (const float*)d_in[6];
    const float* b2     = (const float*)d_in[7];

    const int M = in_sizes[0] / 3;               // 524288
    float* density = (float*)d_out;
    float* seg     = density + M;

    const size_t gt_b   = (size_t)NMOD * NVOX * FDIM * sizeof(_Float16);   // 48 MiB
    const size_t wb_b   = 32768;
    const size_t hist_b = (size_t)NREP * NCELL * sizeof(unsigned int);     // 256 KiB
    const size_t cur_b  = 16;                                              // atomic cursor
    const size_t pts_b  = (size_t)M * sizeof(float4);                      // 8 MiB
    const int nblk = M / TPB;

    if (ws_size >= gt_b + wb_b + hist_b + cur_b + pts_b) {
        char* p = (char*)d_ws;
        _Float16*     gt     = (_Float16*)p;      p += gt_b;
        _Float16*     wbp    = (_Float16*)p;      p += wb_b;
        unsigned int* hist   = (unsigned int*)p;  p += hist_b;
        unsigned int* cursor = (unsigned int*)p;  p += cur_b;
        float4*       pts4   = (float4*)p;

        hipMemsetAsync(hist, 0, hist_b + cur_b, stream);
        pre_kernel<<<TRB + HISTB + PACKB, 256, 0, stream>>>(
            grids, gt, W0, W1, W2, wbp, points, hist, M);
        scan_rep_kernel<<<NCELL / 256, 256, 0, stream>>>(hist, cursor);
        scatter_kernel<<<(M + 255) / 256, 256, 0, stream>>>(points, hist, pts4, M);
        fused_mfma_kernel<true><<<nblk, 256, 0, stream>>>(
            points, pts4, gt, wbp, b0, b1, b2, density, seg);
    } else if (ws_size >= gt_b + wb_b) {
        char* p = (char*)d_ws;
        _Float16* gt  = (_Float16*)p;  p += gt_b;
        _Float16* wbp = (_Float16*)p;
        pre_kernel<<<TRB + HISTB + PACKB, 256, 0, stream>>>(
            grids, gt, W0, W1, W2, wbp, points, (unsigned int*)nullptr, 0);
        fused_mfma_kernel<false><<<nblk, 256, 0, stream>>>(
            points, (const float4*)nullptr, gt, wbp, b0, b1, b2, density, seg);
    } else {
        fused_nerf_fallback<<<nblk, 256, 0, stream>>>(
            points, grids, W0, b0, W1, b1, W2, b2, density, seg);
    }
}